// Round 14
// baseline (92.891 us; speedup 1.0000x reference)
//
#include <hip/hip_runtime.h>
#include <hip/hip_bf16.h>
#include <hip/hip_fp8.h>

#define N 8192
#define D 128
#define WEIGHT 0.01f
#define NTILES 64            // N / 128
#define NBLK 2080            // NTILES*(NTILES+1)/2
#define KSCALE 1.2011224087864498f   // sqrt(log2(e)): sim comes out pre-scaled by log2(e)
#define LN2 0.6931471805599453f

typedef float floatx4 __attribute__((ext_vector_type(4)));

__device__ __forceinline__ float fp8_to_f32(unsigned char b) {
    __hip_fp8_e4m3 v; v.__x = b; return (float)v;
}

// ---- Kernel 1: L2-normalize rows (fp32), scale by KSCALE, store fp8 e4m3
//      XOR-SWIZZLED (16B chunk cc of row r at position cc ^ (r & 7)) so k_gram's
//      linear global_load_lds copy produces a low-conflict LDS layout.
//      With g = KSCALE*f, the gram MFMA produces sim*log2(e): exp(sim)=exp2(acc).
__global__ __launch_bounds__(256) void k_norm(const float* __restrict__ x,
                                              unsigned char* __restrict__ fb8,
                                              float* __restrict__ out) {
    int gid = blockIdx.x * 256 + threadIdx.x;   // 512 blocks
    if (gid == 0) out[0] = 0.0f;
    int row = gid >> 4;                          // 16 threads per row
    int c   = gid & 15;                          // 8 floats -> 8 fp8 bytes per thread
    const float4* xr = (const float4*)(x + (size_t)row * D + c * 8);
    float4 f0 = xr[0], f1 = xr[1];
    float s = f0.x * f0.x + f0.y * f0.y + f0.z * f0.z + f0.w * f0.w
            + f1.x * f1.x + f1.y * f1.y + f1.z * f1.z + f1.w * f1.w;
    s += __shfl_xor(s, 1, 64);
    s += __shfl_xor(s, 2, 64);
    s += __shfl_xor(s, 4, 64);
    s += __shfl_xor(s, 8, 64);                   // 16-lane group = one row
    float inv = KSCALE / fmaxf(sqrtf(s), 1e-12f);
    union { unsigned char b[8]; uint2 u; } pk;
    pk.b[0] = __hip_fp8_e4m3(f0.x * inv).__x;
    pk.b[1] = __hip_fp8_e4m3(f0.y * inv).__x;
    pk.b[2] = __hip_fp8_e4m3(f0.z * inv).__x;
    pk.b[3] = __hip_fp8_e4m3(f0.w * inv).__x;
    pk.b[4] = __hip_fp8_e4m3(f1.x * inv).__x;
    pk.b[5] = __hip_fp8_e4m3(f1.y * inv).__x;
    pk.b[6] = __hip_fp8_e4m3(f1.z * inv).__x;
    pk.b[7] = __hip_fp8_e4m3(f1.w * inv).__x;
    int cc = c >> 1, h = c & 1;                  // 16B chunk + 8B half
    ((uint2*)fb8)[(size_t)row * 16 + (((cc ^ (row & 7)) << 1) | h)] = pk.u;
}

// ---- Kernel 2: upper-triangle 128x128 tiles of sim*log2e = G G^T, fp8 MFMA.
//      exp(sim) = exp2f(acc) -- one native v_exp_f32 per element.
//      Only diagonal tiles (bj==bi) need the strict-upper mask; p/ep extraction
//      moved to k_tail. LDS 34 KB -> 4 blocks/CU. 4 waves (2x2), 64x64/wave.
__global__ __launch_bounds__(256, 4) void k_gram(const unsigned char* __restrict__ fb8,
                                                 float* __restrict__ Prow,
                                                 float* __restrict__ Pcol) {
    int b = blockIdx.x;                  // 0 .. 2079
    int bi = (int)((2.0 * NTILES + 1.0 - sqrt((2.0 * NTILES + 1.0) * (2.0 * NTILES + 1.0) - 8.0 * (double)b)) * 0.5);
    while (bi * NTILES - bi * (bi - 1) / 2 > b) --bi;
    while ((bi + 1) * NTILES - (bi + 1) * bi / 2 <= b) ++bi;
    int bj = bi + (b - (bi * NTILES - bi * (bi - 1) / 2));

    __shared__ uint4 Ab[1024];           // 128 rows x 128 fp8, pre-swizzled (16 KB)
    __shared__ uint4 Bb[1024];
    __shared__ float PR[2][128];
    __shared__ float PC[2][128];

    const int t = threadIdx.x;
    const int lane = t & 63;
    const int wid  = t >> 6;             // 4 waves, 2x2
    const int wrow = wid >> 1, wcol = wid & 1;
    const int col0 = lane & 15;
    const int quad = lane >> 4;
    const int rbase = bi * 128, cbase = bj * 128;

    const uint4* gA = (const uint4*)fb8 + (size_t)rbase * 8;   // 8 chunks/row
    const uint4* gB = (const uint4*)fb8 + (size_t)cbase * 8;
    #pragma unroll
    for (int i = 0; i < 4; ++i) {
        int ca = wid * 256 + i * 64;     // wave-uniform chunk base; lane adds *16B
        __builtin_amdgcn_global_load_lds(
            (const __attribute__((address_space(1))) void*)(gA + ca + lane),
            (__attribute__((address_space(3))) void*)&Ab[ca], 16, 0, 0);
        __builtin_amdgcn_global_load_lds(
            (const __attribute__((address_space(1))) void*)(gB + ca + lane),
            (__attribute__((address_space(3))) void*)&Bb[ca], 16, 0, 0);
    }
    __syncthreads();

    floatx4 acc[4][4];
    #pragma unroll
    for (int a = 0; a < 4; ++a)
        #pragma unroll
        for (int c = 0; c < 4; ++c)
            acc[a][c] = (floatx4){0.0f, 0.0f, 0.0f, 0.0f};

    const long* A8 = (const long*)Ab;    // row = 16 x 8B units
    const long* B8 = (const long*)Bb;
    const int swz = (col0 & 7);
    #pragma unroll
    for (int ks = 0; ks < 4; ++ks) {     // K = 128 = 4 x 32
        long af[4], bfr[4];
        int cc = ks * 2 + (quad >> 1);   // 16B chunk holding k = ks*32 + quad*8
        int off = quad & 1;              // 8B half
        int base8 = ((cc ^ swz) << 1) | off;
        #pragma unroll
        for (int mt = 0; mt < 4; ++mt) { // A[m=lane&15][k=quad*8+j]
            int rl = wrow * 64 + mt * 16 + col0;
            af[mt] = A8[rl * 16 + base8];
        }
        #pragma unroll
        for (int nt = 0; nt < 4; ++nt) { // B^T[n=lane&15][k]
            int cl = wcol * 64 + nt * 16 + col0;
            bfr[nt] = B8[cl * 16 + base8];
        }
        #pragma unroll
        for (int mt = 0; mt < 4; ++mt)
            #pragma unroll
            for (int nt = 0; nt < 4; ++nt)
                acc[mt][nt] = __builtin_amdgcn_mfma_f32_16x16x32_fp8_fp8(af[mt], bfr[nt], acc[mt][nt], 0, 0, 0);
    }

    float v[16];
    float colpart[4];
    #pragma unroll
    for (int m = 0; m < 16; ++m) v[m] = 0.0f;
    #pragma unroll
    for (int m = 0; m < 4; ++m) colpart[m] = 0.0f;

    if (bj > bi) {                       // off-diagonal: all strictly upper
        #pragma unroll
        for (int mt = 0; mt < 4; ++mt)
            #pragma unroll
            for (int nt = 0; nt < 4; ++nt)
                #pragma unroll
                for (int reg = 0; reg < 4; ++reg) {
                    float e = exp2f(acc[mt][nt][reg]);   // native v_exp_f32
                    v[mt * 4 + reg] += e;
                    colpart[nt] += e;
                }
    } else {                             // diagonal tile: strict-upper mask
        #pragma unroll
        for (int mt = 0; mt < 4; ++mt)
            #pragma unroll
            for (int nt = 0; nt < 4; ++nt)
                #pragma unroll
                for (int reg = 0; reg < 4; ++reg) {
                    int rl = wrow * 64 + mt * 16 + quad * 4 + reg;
                    int cl = wcol * 64 + nt * 16 + col0;
                    float e = exp2f(acc[mt][nt][reg]);
                    e = (cl > rl) ? e : 0.0f;
                    v[mt * 4 + reg] += e;
                    colpart[nt] += e;
                }
    }

    // Row sums: value-halving butterfly (15 shuffles, all lanes distinct rows).
    float v8[8];
    #pragma unroll
    for (int k = 0; k < 8; ++k) {
        float a = v[2 * k], bb = v[2 * k + 1];
        float give = (lane & 1) ? a : bb;
        float keep = (lane & 1) ? bb : a;
        v8[k] = keep + __shfl_xor(give, 1, 64);
    }
    float v4[4];
    #pragma unroll
    for (int k = 0; k < 4; ++k) {
        float a = v8[2 * k], bb = v8[2 * k + 1];
        float give = (lane & 2) ? a : bb;
        float keep = (lane & 2) ? bb : a;
        v4[k] = keep + __shfl_xor(give, 2, 64);
    }
    float v2[2];
    #pragma unroll
    for (int k = 0; k < 2; ++k) {
        float a = v4[2 * k], bb = v4[2 * k + 1];
        float give = (lane & 4) ? a : bb;
        float keep = (lane & 4) ? bb : a;
        v2[k] = keep + __shfl_xor(give, 4, 64);
    }
    {
        float a = v2[0], bb = v2[1];
        float give = (lane & 8) ? a : bb;
        float keep = (lane & 8) ? bb : a;
        float v1 = keep + __shfl_xor(give, 8, 64);
        int rowl = wrow * 64 + (col0 >> 2) * 16 + quad * 4 + (col0 & 3);
        PR[wcol][rowl] = v1;
    }
    {
        float c2[2];
        #pragma unroll
        for (int k = 0; k < 2; ++k) {
            float a = colpart[2 * k];
            float bb = colpart[2 * k + 1];
            float give = (lane & 16) ? a : bb;
            float keep = (lane & 16) ? bb : a;
            c2[k] = keep + __shfl_xor(give, 16, 64);
        }
        float a = c2[0], bb = c2[1];
        float give = (lane & 32) ? a : bb;
        float keep = (lane & 32) ? bb : a;
        float cv = keep + __shfl_xor(give, 32, 64);
        PC[wrow][wcol * 64 + lane] = cv;
    }
    __syncthreads();

    if (t < 128) {
        Prow[(size_t)b * 128 + t] = PR[0][t] + PR[1][t];
    } else {
        int c = t - 128;
        Pcol[(size_t)b * 128 + c] = PC[0][c] + PC[1][c];
    }
}

// ---- Kernel 3 (merged reduce+final): per band of 128 rows: p/ep via an fp8
//      VALU dot of adjacent rows (registers only), U in registers, L via LDS,
//      log terms, block-reduce, one scaled atomicAdd into out[0].
__global__ __launch_bounds__(256) void k_tail(const unsigned char* __restrict__ fb8,
                                              const float* __restrict__ Prow,
                                              const float* __restrict__ Pcol,
                                              float* __restrict__ out) {
    __shared__ float Lsh[128];           // Lsh[i] = L[band*128 + i + 1]
    __shared__ float sw[4];
    int band = blockIdx.x;               // 0..63
    int t = threadIdx.x;
    float Ureg = 0.0f, pp = 0.0f;        // pp = log2(e) * sim(r, r+1)
    if (t < 128) {
        int r = band * 128 + t;
        if (r < N - 1) {
            const uint4* g = (const uint4*)fb8;
            float s = 0.0f;
            #pragma unroll
            for (int cc = 0; cc < 8; ++cc) {
                union { uint4 u; unsigned char b[16]; } ua, ub;
                ua.u = g[(size_t)r * 8 + (cc ^ (r & 7))];
                ub.u = g[(size_t)(r + 1) * 8 + (cc ^ ((r + 1) & 7))];
                #pragma unroll
                for (int k = 0; k < 16; ++k)
                    s += fp8_to_f32(ua.b[k]) * fp8_to_f32(ub.b[k]);
            }
            pp = s;
        }
        int baseU = band * NTILES - band * (band - 1) / 2;
        float s = 0.0f;
        for (int bj = band; bj < NTILES; ++bj)
            s += Prow[(size_t)(baseU + bj - band) * 128 + t];
        Ureg = s;
    } else {
        int c = band * 128 + (t - 128) + 1;      // base+1 .. base+128
        float s = 0.0f;
        if (c < N) {
            int bc = c >> 7;
            for (int bi = 0; bi <= bc; ++bi)
                s += Pcol[(size_t)(bi * NTILES - bi * (bi - 1) / 2 + (bc - bi)) * 128 + (c & 127)];
        }
        Lsh[t - 128] = s;
    }
    __syncthreads();
    float term = 0.0f;
    if (t < 128) {
        int r = band * 128 + t;
        if (r < N - 1)
            term = __logf(Ureg + Lsh[t] - exp2f(pp)) - LN2 * pp;
    }
    #pragma unroll
    for (int m = 1; m < 64; m <<= 1) term += __shfl_xor(term, m, 64);
    int lane = t & 63, wd = t >> 6;
    if (lane == 0) sw[wd] = term;
    __syncthreads();
    if (t == 0) {
        float part = sw[0] + sw[1] + sw[2] + sw[3];
        atomicAdd(out, -WEIGHT * part / (float)N);
    }
}

extern "C" void kernel_launch(void* const* d_in, const int* in_sizes, int n_in,
                              void* d_out, int out_size, void* d_ws, size_t ws_size,
                              hipStream_t stream) {
    const float* x = (const float*)d_in[0];
    float* out = (float*)d_out;
    char* ws = (char*)d_ws;
    unsigned char* fb8 = (unsigned char*)ws;                   // N*D = 1 MB
    float* Prow = (float*)(ws + (size_t)N * D);                // NBLK*128 floats
    float* Pcol = Prow + (size_t)NBLK * 128;

    hipLaunchKernelGGL(k_norm, dim3(512),  dim3(256), 0, stream, x, fb8, out);
    hipLaunchKernelGGL(k_gram, dim3(NBLK), dim3(256), 0, stream, fb8, Prow, Pcol);
    hipLaunchKernelGGL(k_tail, dim3(64),   dim3(256), 0, stream, fb8, Prow, Pcol, out);
}